// Round 4
// baseline (360.210 us; speedup 1.0000x reference)
//
#include <hip/hip_runtime.h>

#define NRAYS   262144
#define TCOARSE 64
#define NSAMP   256
#define RPB     16
#define TFINALF 1e10f
#define EPSF    1e-5f
#define SSTR    258   // ≡ 2 (mod 32): transpose reads are exact 2-way (free)

// ---- DPP helpers (VALU cross-lane, no DS pipe) ----
template<int CTRL, int RMASK = 0xF>
__device__ __forceinline__ float dppf(float x) {
    return __int_as_float(
        __builtin_amdgcn_update_dpp(0, __float_as_int(x), CTRL, RMASK, 0xF, false));
}

// wave64 inclusive +scan: 4 row_shr steps + row_bcast15/31 carries
__device__ __forceinline__ float wave_iscan(float x) {
    x += dppf<0x111>(x);           // row_shr:1
    x += dppf<0x112>(x);           // row_shr:2
    x += dppf<0x114>(x);           // row_shr:4
    x += dppf<0x118>(x);           // row_shr:8
    x += dppf<0x142, 0xA>(x);      // row_bcast15 -> rows 1,3
    x += dppf<0x143, 0xC>(x);      // row_bcast31 -> rows 2,3
    return x;
}

template<int LX>
__device__ __forceinline__ float xchg(float x, int lane) {
    if constexpr (LX == 1)      return dppf<0xB1>(x);                 // quad_perm [1,0,3,2]
    else if constexpr (LX == 2) return dppf<0x4E>(x);                 // quad_perm [2,3,0,1]
    else if constexpr (LX == 4) {
        float a = dppf<0x104>(x);  // row_shl:4
        float b = dppf<0x114>(x);  // row_shr:4
        return (lane & 4) ? b : a;
    } else if constexpr (LX == 8) {
        float a = dppf<0x108>(x);  // row_shl:8
        float b = dppf<0x118>(x);  // row_shr:8
        return (lane & 8) ? b : a;
    } else {
        return __shfl_xor(x, LX);  // 16, 32: DS crossbar
    }
}

__device__ __forceinline__ void sort2c(float& a, float& b, bool asc) {
    float mn = fminf(a, b), mx = fmaxf(a, b);
    a = asc ? mn : mx;
    b = asc ? mx : mn;
}

template<int KK, int JS>
__device__ __forceinline__ void crosspass(float v[4], int lane, bool asc) {
    if constexpr (JS >= 4) {
        constexpr int LX = JS >> 2;
        bool keepmin = (asc == ((lane & LX) == 0));
        #pragma unroll
        for (int j = 0; j < 4; ++j) {
            float o = xchg<LX>(v[j], lane);
            float mn = fminf(v[j], o), mx = fmaxf(v[j], o);
            v[j] = keepmin ? mn : mx;
        }
        crosspass<KK, JS / 2>(v, lane, asc);
    }
}

template<int KK>
__device__ __forceinline__ void stage(float v[4], int lane) {
    bool asc = (lane & (KK >> 2)) == 0;
    crosspass<KK, KK / 2>(v, lane, asc);
    sort2c(v[0], v[2], asc); sort2c(v[1], v[3], asc);
    sort2c(v[0], v[1], asc); sort2c(v[2], v[3], asc);
}

__device__ __forceinline__ void sort256(float v[4], int lane) {
    { float mn = fminf(v[0], v[1]), mx = fmaxf(v[0], v[1]); v[0] = mn; v[1] = mx; }
    { float mn = fminf(v[2], v[3]), mx = fmaxf(v[2], v[3]); v[2] = mx; v[3] = mn; }
    { bool asc = (lane & 1) == 0;
      sort2c(v[0], v[2], asc); sort2c(v[1], v[3], asc);
      sort2c(v[0], v[1], asc); sort2c(v[2], v[3], asc); }
    stage<8>(v, lane);  stage<16>(v, lane);  stage<32>(v, lane);
    stage<64>(v, lane); stage<128>(v, lane); stage<256>(v, lane);
}

__global__ __launch_bounds__(256, 7) void informed_sampler_kernel(
    const float* __restrict__ tnear,
    const float* __restrict__ tfar,
    const float* __restrict__ dnorm,
    const float* __restrict__ density,
    const float* __restrict__ u,
    float* __restrict__ out)
{
    __shared__ float s_dens[TCOARSE * (RPB + 1)];   // [64][17]: col reads 2-way (free)
    __shared__ float s_sort[RPB * SSTR];            // [16][258]
    __shared__ float s_tn[RPB], s_td[RPB], s_dn[RPB];

    const int tid  = threadIdx.x;
    const int lane = tid & 63;
    const int wid  = tid >> 6;
    const int r0   = blockIdx.x * RPB;

    const float4* ub = reinterpret_cast<const float4*>(u);
    float4 uu = ub[(size_t)(r0 + wid) * (NSAMP / 4) + lane];   // prefetch ray k=0

    if (tid < RPB) {
        float tn = tnear[r0 + tid];
        float tf = tfar [r0 + tid];
        s_tn[tid] = tn;
        s_td[tid] = tf - tn;
        s_dn[tid] = dnorm[r0 + tid];
    }
    #pragma unroll
    for (int it = 0; it < 4; ++it) {
        int i = it * 16 + (tid >> 4);
        int c = tid & 15;
        s_dens[i * (RPB + 1) + c] = density[(size_t)i * NRAYS + r0 + c];
    }
    __syncthreads();

    #pragma unroll 1
    for (int k = 0; k < 4; ++k) {
        const int c = k * 4 + wid;
        const float tn = s_tn[c], td = s_td[c], dn = s_dn[c];
        const float tf = tn + td;

        // prefetch next ray's u (issued early, consumed next iteration)
        float4 un = uu;
        if (k < 3) un = ub[(size_t)(r0 + c + 4) * (NSAMP / 4) + lane];

        // ---- CDF build: register-resident, lane l ends holding cdf[l+1] ----
        float tsl   = tn + td * ((float)lane * (1.0f / 63.0f));
        float tsn_  = tn + td * ((float)(lane + 1) * (1.0f / 63.0f));
        float delta = (lane < TCOARSE - 1) ? (tsn_ - tsl) : (TFINALF - tsl);
        float sd    = s_dens[lane * (RPB + 1) + c] * delta * dn;

        float inc  = wave_iscan(sd);
        float sh   = __shfl_up(inc, 1);
        float excl = (lane == 0) ? 0.0f : sh;   // exact exclusive (no cancellation)
        float wv   = __expf(-excl) * (1.0f - __expf(-sd)) + EPSF;

        float incw  = wave_iscan(wv);
        float total = __int_as_float(__builtin_amdgcn_readlane(__float_as_int(incw), 63));
        float cdfreg = incw / total;            // cdf[lane+1]; cdf[0] == 0

        // ---- inverse-CDF sampling: bpermute binary search (conflict-free) ----
        float v[4] = {uu.x, uu.y, uu.z, uu.w};
        #pragma unroll
        for (int j = 0; j < 4; ++j) {
            float uq = v[j];
            int b = 0;                           // largest b in [0,63] with cdf[b] <= uq
            #pragma unroll
            for (int s = 32; s >= 1; s >>= 1) {
                float cv = __shfl(cdfreg, b + s - 1);   // cdf[b+s], index >= 1 always
                b += (cv <= uq) ? s : 0;
            }
            float cbs = __shfl(cdfreg, b - 1);   // garbage if b==0, selected away
            float cb  = (b == 0) ? 0.0f : cbs;
            float ca  = __shfl(cdfreg, b);       // cdf[b+1]
            float denom = ca - cb;
            denom = (denom < EPSF) ? 1.0f : denom;
            float fb = (float)b;
            float eb = (b == 0)  ? tn : tn + td * ((fb - 0.5f) * (1.0f / 63.0f));
            float ea = (b == 63) ? tf : tn + td * ((fb + 0.5f) * (1.0f / 63.0f));
            float smp = eb + ((uq - cb) / denom) * (ea - eb);
            v[j] = fminf(fmaxf(smp, tn), tf);    // exact bounds; NaN-absorbing
        }

        // ---- wave bitonic sort (DPP; DS only for xor16/32) ----
        sort256(v, lane);

        float* srow = &s_sort[c * SSTR];
        #pragma unroll
        for (int j = 0; j < 4; ++j) srow[lane * 4 + j] = v[j];

        uu = un;
    }
    __syncthreads();

    // ---- transposed coalesced output, out[s*N + r] ----
    #pragma unroll
    for (int it = 0; it < 16; ++it) {
        int s = it * 16 + (tid >> 4);
        int c = tid & 15;
        out[(size_t)s * NRAYS + r0 + c] = s_sort[c * SSTR + s];
    }
}

extern "C" void kernel_launch(void* const* d_in, const int* in_sizes, int n_in,
                              void* d_out, int out_size, void* d_ws, size_t ws_size,
                              hipStream_t stream) {
    const float* tnear   = (const float*)d_in[0];
    const float* tfar    = (const float*)d_in[1];
    const float* dnorm   = (const float*)d_in[2];
    const float* density = (const float*)d_in[3];
    const float* u       = (const float*)d_in[4];
    float* out = (float*)d_out;

    dim3 grid(NRAYS / RPB);
    dim3 block(256);
    hipLaunchKernelGGL(informed_sampler_kernel, grid, block, 0, stream,
                       tnear, tfar, dnorm, density, u, out);
}

// Round 5
// 206.724 us; speedup vs baseline: 1.7425x; 1.7425x over previous
//
#include <hip/hip_runtime.h>
#include <stdint.h>

#define NRAYS   262144
#define NSAMP   256
#define RPB     16
#define TFINALF 1e10f
#define EPSF    1e-5f
#define CSTR    68     // cdf row stride (floats): rows 16B-aligned, 4-bank skew/row
#define SSTR    316    // sort-stage row stride (floats)
#define SKEW    20     // in-row skew per lane (floats): b128-aligned, spread banks

template<int CTRL>
__device__ __forceinline__ uint32_t dppi(uint32_t x) {
    return (uint32_t)__builtin_amdgcn_update_dpp(0, (int)x, CTRL, 0xF, 0xF, false);
}
template<int CTRL>
__device__ __forceinline__ float dppf(float x) {
    return __int_as_float(__builtin_amdgcn_update_dpp(0, __float_as_int(x), CTRL, 0xF, 0xF, false));
}

// inclusive +scan across a 16-lane DPP row (groups align with rows)
__device__ __forceinline__ float row16_iscan(float x) {
    x += dppf<0x111>(x);   // row_shr:1 (0-fill at row edge)
    x += dppf<0x112>(x);
    x += dppf<0x114>(x);
    x += dppf<0x118>(x);
    return x;
}

// compare-exchange, raw-bits domain (positive floats: u32 order == float order)
__device__ __forceinline__ void ce(uint32_t& a, uint32_t& b, bool up) {
    uint32_t mn = min(a, b), mx = max(a, b);
    a = up ? mx : mn;
    b = up ? mn : mx;
}

// in-lane pass, complement domain: min always at lower element
template<int JS>
__device__ __forceinline__ void pmin(uint32_t w[16]) {
#pragma unroll
    for (int j = 0; j < 16; ++j)
        if ((j & JS) == 0) {
            uint32_t mn = min(w[j], w[j + JS]), mx = max(w[j], w[j + JS]);
            w[j] = mn; w[j + JS] = mx;
        }
}

// cross-lane pass (lane-stride LX within the 16-lane row), complement domain
template<int LX>
__device__ __forceinline__ void pcross(uint32_t w[16], bool up) {
#pragma unroll
    for (int j = 0; j < 16; ++j) {
        uint32_t pa, pb;
        if constexpr (LX == 1)      { pa = dppi<0xB1>(w[j]);  pb = dppi<0xB1>(w[j]);  } // quad_perm xor1
        else if constexpr (LX == 2) { pa = dppi<0x4E>(w[j]);  pb = dppi<0x4E>(w[j]);  } // quad_perm xor2
        else if constexpr (LX == 4) { pa = dppi<0x104>(w[j]); pb = dppi<0x114>(w[j]); } // shl4 / shr4
        else                        { pa = dppi<0x108>(w[j]); pb = dppi<0x118>(w[j]); } // shl8 / shr8
        uint32_t mn = min(w[j], pa), mx = max(w[j], pb);
        w[j] = up ? mx : mn;
    }
}

__global__ __launch_bounds__(256, 6) void informed_sampler_kernel(
    const float* __restrict__ tnear,
    const float* __restrict__ tfar,
    const float* __restrict__ dnorm,
    const float* __restrict__ density,
    const float* __restrict__ u,
    float* __restrict__ out)
{
    __shared__ float s_cdf[8 + RPB * CSTR];   // row c at 8 + c*68; row[i] = cdf[i+1]
    __shared__ float s_sort[RPB * SSTR];      // rank e of ray c at c*316 + (e>>4)*20 + (e&15)

    const int tid  = threadIdx.x;
    const int lane = tid & 63;
    const int wid  = tid >> 6;
    const int g    = lane >> 4;     // group (ray) within wave
    const int lp   = lane & 15;     // lane within 16-lane group
    const int c    = wid * 4 + g;   // ray within block
    const int r    = blockIdx.x * RPB + c;

    const float tn  = tnear[r];
    const float tff = tfar[r];
    const float dn  = dnorm[r];
    const float td  = tff - tn;
    const float inv63 = 1.0f / 63.0f;

    // ---- load u: lane lp holds elements e = lp*16 + j (any initial perm is fine) ----
    const float4* ub = reinterpret_cast<const float4*>(u + (size_t)r * NSAMP);
    uint32_t w[16];
    {
        float4 a0 = ub[lp*4+0], a1 = ub[lp*4+1], a2 = ub[lp*4+2], a3 = ub[lp*4+3];
        w[ 0]=__float_as_uint(a0.x); w[ 1]=__float_as_uint(a0.y); w[ 2]=__float_as_uint(a0.z); w[ 3]=__float_as_uint(a0.w);
        w[ 4]=__float_as_uint(a1.x); w[ 5]=__float_as_uint(a1.y); w[ 6]=__float_as_uint(a1.z); w[ 7]=__float_as_uint(a1.w);
        w[ 8]=__float_as_uint(a2.x); w[ 9]=__float_as_uint(a2.y); w[10]=__float_as_uint(a2.z); w[11]=__float_as_uint(a2.w);
        w[12]=__float_as_uint(a3.x); w[13]=__float_as_uint(a3.y); w[14]=__float_as_uint(a3.z); w[15]=__float_as_uint(a3.w);
    }

    // ---- CDF build: lane lp owns bins b0..b0+3 ----
    const int b0 = lp * 4;
    float de0 = density[(size_t)(b0+0)*NRAYS + r];
    float de1 = density[(size_t)(b0+1)*NRAYS + r];
    float de2 = density[(size_t)(b0+2)*NRAYS + r];
    float de3 = density[(size_t)(b0+3)*NRAYS + r];

    float dl  = td * inv63;
    float t3  = tn + td * ((float)(b0+3) * inv63);
    float dl3 = (lp == 15) ? (TFINALF - t3) : dl;
    float sd0 = de0 * dl * dn, sd1 = de1 * dl * dn, sd2 = de2 * dl * dn, sd3 = de3 * dl3 * dn;

    float p0 = sd0, p1 = p0 + sd1, p2 = p1 + sd2, p3 = p2 + sd3;
    float tsc   = row16_iscan(p3);
    float carry = dppf<0x111>(tsc);              // exclusive lane-carry (no cancellation)
    float x0 = carry, x1 = carry + p0, x2 = carry + p1, x3 = carry + p2;
    float wv0 = __expf(-x0) * (1.0f - __expf(-sd0)) + EPSF;
    float wv1 = __expf(-x1) * (1.0f - __expf(-sd1)) + EPSF;
    float wv2 = __expf(-x2) * (1.0f - __expf(-sd2)) + EPSF;
    float wv3 = __expf(-x3) * (1.0f - __expf(-sd3)) + EPSF;
    float q0 = wv0, q1 = q0 + wv1, q2 = q1 + wv2, q3 = q2 + wv3;
    float tww = row16_iscan(q3);
    float cw  = dppf<0x111>(tww);
    float tot = __int_as_float(__builtin_amdgcn_ds_swizzle(__float_as_int(tww), 0x1F0)); // bcast lane15 of 16-group
    float inv = __builtin_amdgcn_rcpf(tot);

    float* cdfrow = &s_cdf[8 + c * CSTR];
    *reinterpret_cast<float4*>(cdfrow + b0) =
        make_float4((cw+q0)*inv, (cw+q1)*inv, (cw+q2)*inv, (cw+q3)*inv);
    __asm__ volatile("s_waitcnt lgkmcnt(0)" ::: "memory");   // wave-local: own group's writes visible
    __builtin_amdgcn_sched_barrier(0);

    // ---- bitonic sort of 256 u across the 16-lane group, e = lp*16 + j ----
    // stages 2,4,8: static directions on raw bits
#pragma unroll
    for (int j = 0; j < 16; j += 2) ce(w[j], w[j+1], (j & 2) != 0);
#pragma unroll
    for (int j = 0; j < 16; ++j) if ((j & 2) == 0) ce(w[j], w[j+2], (j & 4) != 0);
#pragma unroll
    for (int j = 0; j < 16; j += 2) ce(w[j], w[j+1], (j & 4) != 0);
#pragma unroll
    for (int j = 0; j < 16; ++j) if ((j & 4) == 0) ce(w[j], w[j+4], (j & 8) != 0);
#pragma unroll
    for (int j = 0; j < 16; ++j) if ((j & 2) == 0) ce(w[j], w[j+2], (j & 8) != 0);
#pragma unroll
    for (int j = 0; j < 16; j += 2) ce(w[j], w[j+1], (j & 8) != 0);

    const uint32_t m16  = (lp & 1) ? 0xFFFFFFFFu : 0u;
    const uint32_t m32  = (lp & 2) ? 0xFFFFFFFFu : 0u;
    const uint32_t m64  = (lp & 4) ? 0xFFFFFFFFu : 0u;
    const uint32_t m128 = (lp & 8) ? 0xFFFFFFFFu : 0u;
    const bool u1 = (lp & 1) != 0, u2 = (lp & 2) != 0, u4 = (lp & 4) != 0, u8 = (lp & 8) != 0;

    { uint32_t mm = m16;
#pragma unroll
      for (int j = 0; j < 16; ++j) w[j] ^= mm; }
    pmin<8>(w); pmin<4>(w); pmin<2>(w); pmin<1>(w);                       // stage 16
    { uint32_t mm = m16 ^ m32;
#pragma unroll
      for (int j = 0; j < 16; ++j) w[j] ^= mm; }
    pcross<1>(w, u1);
    pmin<8>(w); pmin<4>(w); pmin<2>(w); pmin<1>(w);                       // stage 32
    { uint32_t mm = m32 ^ m64;
#pragma unroll
      for (int j = 0; j < 16; ++j) w[j] ^= mm; }
    pcross<2>(w, u2); pcross<1>(w, u1);
    pmin<8>(w); pmin<4>(w); pmin<2>(w); pmin<1>(w);                       // stage 64
    { uint32_t mm = m64 ^ m128;
#pragma unroll
      for (int j = 0; j < 16; ++j) w[j] ^= mm; }
    pcross<4>(w, u4); pcross<2>(w, u2); pcross<1>(w, u1);
    pmin<8>(w); pmin<4>(w); pmin<2>(w); pmin<1>(w);                       // stage 128
    { uint32_t mm = m128;
#pragma unroll
      for (int j = 0; j < 16; ++j) w[j] ^= mm; }
    pcross<8>(w, u8); pcross<4>(w, u4); pcross<2>(w, u2); pcross<1>(w, u1);
    pmin<8>(w); pmin<4>(w); pmin<2>(w); pmin<1>(w);                       // stage 256
    // w now = sorted u bits, ascending in e = lp*16 + j

    // ---- inverse-CDF (clustered LDS search; sorted in == sorted out) ----
    float* srow = &s_sort[c * SSTR + lp * SKEW];
    float sm[4];
#pragma unroll
    for (int j = 0; j < 16; ++j) {
        float uq = __uint_as_float(w[j]);
        int b = 0;                       // b = #{i in 0..63 : row[i] <= uq}, row[i]=cdf[i+1]
#pragma unroll
        for (int s = 32; s >= 1; s >>= 1)
            if (cdfrow[b + s - 1] <= uq) b += s;
        float cbm = cdfrow[b - 1];       // b=0 reads pad (discarded below)
        float ca  = cdfrow[b];
        float cb  = (b == 0) ? 0.0f : cbm;
        float dnm = ca - cb;
        dnm = (dnm < EPSF) ? 1.0f : dnm;
        float fb = (float)b;
        float eb = (b == 0)  ? tn  : tn + td * ((fb - 0.5f) * inv63);
        float ea = (b == 63) ? tff : tn + td * ((fb + 0.5f) * inv63);
        float t  = (uq - cb) * __builtin_amdgcn_rcpf(dnm);
        float smp = eb + t * (ea - eb);
        sm[j & 3] = fminf(fmaxf(smp, tn), tff);   // exact bounds; NaN-absorbing
        if ((j & 3) == 3)
            *reinterpret_cast<float4*>(srow + (j - 3)) = make_float4(sm[0], sm[1], sm[2], sm[3]);
    }
    __syncthreads();

    // ---- transposed coalesced output, out[s*N + r] ----
#pragma unroll
    for (int it = 0; it < 16; ++it) {
        int s  = it * 16 + (tid >> 4);
        int cc = tid & 15;
        out[(size_t)s * NRAYS + blockIdx.x * RPB + cc] =
            s_sort[cc * SSTR + it * SKEW + (tid >> 4)];
    }
}

extern "C" void kernel_launch(void* const* d_in, const int* in_sizes, int n_in,
                              void* d_out, int out_size, void* d_ws, size_t ws_size,
                              hipStream_t stream) {
    const float* tnear   = (const float*)d_in[0];
    const float* tfar    = (const float*)d_in[1];
    const float* dnorm   = (const float*)d_in[2];
    const float* density = (const float*)d_in[3];
    const float* u       = (const float*)d_in[4];
    float* out = (float*)d_out;

    dim3 grid(NRAYS / RPB);
    dim3 block(256);
    hipLaunchKernelGGL(informed_sampler_kernel, grid, block, 0, stream,
                       tnear, tfar, dnorm, density, u, out);
}